// Round 9
// baseline (181.238 us; speedup 1.0000x reference)
//
#include <hip/hip_runtime.h>
#include <hip/hip_bf16.h>

typedef __bf16 bf16x8 __attribute__((ext_vector_type(8)));
typedef float f32x4 __attribute__((ext_vector_type(4)));
typedef float f32x16 __attribute__((ext_vector_type(16)));
typedef unsigned short u16;
typedef unsigned int u32;

__device__ __forceinline__ u16 f2bf_rne(float f){
  union { float f; u32 u; } v; v.f = f;
  u32 r = v.u + 0x7fffu + ((v.u >> 16) & 1u);
  return (u16)(r >> 16);
}
// async global->LDS, 16B per lane (dest = wave-uniform base + lane*16)
__device__ __forceinline__ void load_lds16(const void* g, void* l){
  __builtin_amdgcn_global_load_lds((const __attribute__((address_space(1))) void*)g,
                                   (__attribute__((address_space(3))) void*)l, 16, 0, 0);
}
#define BARRIER_LGKM() asm volatile("s_waitcnt lgkmcnt(0)\n\ts_barrier" ::: "memory")

// ------------- prep: Wfrag = [Wh|Wf|Wg]^T in MFMA B-fragment order -------------
// Wfrag[cc(20)][kk(8)][lane(64)][j(8)] bf16; lane=(quad,L):
//   element = Wcat[k = kk*32 + quad*8 + j][n = cc*16 + L]
__global__ __launch_bounds__(512) void prep_kernel(
    const float* __restrict__ Wf, const float* __restrict__ Wg,
    const float* __restrict__ Wh, u16* __restrict__ Wfrag){
  const int cc = blockIdx.x;             // 20
  const int t = threadIdx.x;             // 512 = kk(8) x lane(64)
  const int kk = t >> 6, lane = t & 63;
  const int L = lane & 15, quad = lane >> 4;
  const int n = cc * 16 + L;
  u32 pk[4];
  #pragma unroll
  for (int j2 = 0; j2 < 4; ++j2){
    float v[2];
    #pragma unroll
    for (int h = 0; h < 2; ++h){
      int k = kk * 32 + quad * 8 + j2 * 2 + h;
      if (n < 256)      v[h] = Wh[k * 256 + n];
      else if (n < 288) v[h] = Wf[k * 32 + (n - 256)];
      else              v[h] = Wg[k * 32 + (n - 288)];
    }
    pk[j2] = (u32)f2bf_rne(v[0]) | ((u32)f2bf_rne(v[1]) << 16);
  }
  uint4* dst = (uint4*)(Wfrag + ((size_t)(cc * 8 + kk) * 64 + lane) * 8);
  *dst = make_uint4(pk[0], pk[1], pk[2], pk[3]);
}

// ---------------- projection: h/f/g via MFMA, 512 thr / 8 waves ----------------
// Qg pre-scaled by log2(e), row-major [row][32]. Kg row-major [row][32].
// V emitted fragment-major per 64-row group: Vfrag[g64][p(8)][c(256)][j(8)],
// p = ((tn&15)<<2)|(tn>>4)  (so B-frag read k == p index).
__global__ __launch_bounds__(512) void proj_kernel(
    const float* __restrict__ x, const u16* __restrict__ Wfrag,
    u16* __restrict__ Qg, u16* __restrict__ Kg, u16* __restrict__ Vfrag)
{
  __shared__ __align__(16) u16 smem[256 * 72];   // 36 KB, two phases
  u16 (*xb)[264] = (u16(*)[264])smem;
  u16 (*Vr)[72]  = (u16(*)[72])smem;

  const int tid = threadIdx.x;
  const int lane = tid & 63, wave = tid >> 6;
  const int L = lane & 15, quad = lane >> 4;
  const int rowgrp = wave >> 1, colhalf = wave & 1;
  const int n0 = blockIdx.x * 64;

  const float4* xsrc = (const float4*)(x + (size_t)n0 * 256);
  #pragma unroll
  for (int j = 0; j < 8; ++j){
    int idx = j * 512 + tid;
    int row = idx >> 6, col4 = idx & 63;
    float4 v = xsrc[idx];
    u32 p0 = (u32)f2bf_rne(v.x) | ((u32)f2bf_rne(v.y) << 16);
    u32 p1 = (u32)f2bf_rne(v.z) | ((u32)f2bf_rne(v.w) << 16);
    *(uint2*)&xb[row][col4 * 4] = make_uint2(p0, p1);
  }
  __syncthreads();

  f32x4 acc[10];
  #pragma unroll
  for (int cc = 0; cc < 10; ++cc) acc[cc] = (f32x4){0.f, 0.f, 0.f, 0.f};

  #pragma unroll
  for (int kk = 0; kk < 8; ++kk){
    bf16x8 a = *(const bf16x8*)&xb[rowgrp * 16 + L][kk * 32 + quad * 8];
    #pragma unroll
    for (int cc = 0; cc < 10; ++cc){
      int ccg = colhalf * 10 + cc;
      bf16x8 bfr = *(const bf16x8*)(Wfrag + ((size_t)(ccg * 8 + kk) * 64 + lane) * 8);
      acc[cc] = __builtin_amdgcn_mfma_f32_16x16x32_bf16(a, bfr, acc[cc], 0, 0, 0);
    }
  }

  if (colhalf){
    #pragma unroll
    for (int cc = 6; cc < 10; ++cc){
      int ccg = 10 + cc;                                  // 16..19
      u16* dst = (ccg < 18) ? Kg : Qg;                    // K = f, Q = g
      float sc = (ccg < 18) ? 1.0f : 1.44269504088896f;
      int c = (ccg & 1) * 16 + L;
      #pragma unroll
      for (int r = 0; r < 4; ++r){
        int row = n0 + rowgrp * 16 + quad * 4 + r;
        dst[(size_t)row * 32 + c] = f2bf_rne(acc[cc][r] * sc);
      }
    }
  }

  __syncthreads();   // xb consumed; reuse smem as Vr

  {
    const int cmax = colhalf ? 6 : 10;
    for (int cc = 0; cc < cmax; ++cc){
      int ccg = colhalf * 10 + cc;
      int c = ccg * 16 + L;
      #pragma unroll
      for (int r = 0; r < 4; ++r){
        int tn = rowgrp * 16 + quad * 4 + r;
        int p  = ((tn & 15) << 2) | (tn >> 4);
        Vr[c][p] = f2bf_rne(acc[cc][r]);
      }
    }
  }
  __syncthreads();

  u16* Vblk = Vfrag + (size_t)blockIdx.x * (256 * 64);
  #pragma unroll
  for (int i = 0; i < 4; ++i){
    int idx = i * 512 + tid;
    *(uint4*)(Vblk + (size_t)idx * 8) = *(const uint4*)&Vr[idx & 255][(idx >> 8) * 8];
  }
}

// ---- flash v9: swapped-QK, in-register softmax, NO P round-trip ---------------
// MODEL (R0-R8): time = per-wave serial chain x waves/SIMD; the barrier
// phase-locks waves so TLP (R3) / unroll (R6) / byte cuts (R8) were all null.
// The chain's biggest links were P's LDS round-trip (exp->pack->ds_write->
// lgkm->barrier->ds_read->PV). This kernel removes them:
//  - 512 blocks x 256 thr (4 waves). block = (b, qt:128 q-rows, cq: 64 c-cols).
//    wave = 32 q-rows x 64 c, FULL k (softmax local; no combine; no extra ws).
//    2 blocks/CU -> 2 waves/SIMD from DIFFERENT blocks => de-phased barriers.
//  - QK SWAPPED: s = mfma_32x32x16(A=K(32k x 16d), B=Q(16d x 32q)) x2 k-chunks
//    x2 d-steps. C-layout: row k=(rg&3)+8*(rg>>2)+4*h32, col q=m32 => lane
//    holds 32 P-values of ITS q-row m32 => softmax fully in-register.
//  - P -> PV A-frags in-register: 16 v_cvt_pk_bf16_f32 + 8 v_permlane32_swap
//    (exchanges k{4..7}-style sub-blocks with the h32 partner lane). fr[ks]
//    gives a[q=m32][k=ks*16+h32*8+j] exactly (word-level mapping verified).
//  - PV: O(32q x 64c) += P x V: 8 mfma_32x32x16 (2 cb x 4 ks), B=V from LDS.
//  - V c-quarter (8KB/tile) double-buffered in LDS via global_load_lds; the
//    ONLY barrier gates the stage. Counted vmcnt: at loop top own stage(t)
//    ops are the 2 OLDEST of <=6 tracked => vmcnt(4) drains them regardless
//    of where the compiler schedules the (self-guarded) K register loads.
//  - K read per-wave from global row-major Kg; 4-wave dup is L1-absorbed
//    (proven: R8's K-dedup was perf-null).
// lsum: per-lane partial (its h32 half of k); epilogue: ltot = ls+shfl_xor(32)
// => lanes hold l[q=m32]; per-acc-row scale fetched via __shfl(ltot, rowq).
__global__ __launch_bounds__(256) void flash_kernel(
    const u16* __restrict__ Qg, const u16* __restrict__ Kg, const u16* __restrict__ Vfrag,
    const float* __restrict__ x, const float* __restrict__ gamma, float* __restrict__ out)
{
  constexpr float SH = -92.33248261689366f;      // -64*log2(e); s log2-scaled via Qg
  __shared__ __align__(16) u16 Vl[2][4096];      // [buf][p(8)*512]  (8 KB each)

  const int tid = threadIdx.x, lane = tid & 63, w = tid >> 6;   // w 0..3
  const int m32 = lane & 31, h32 = lane >> 5;

  // id -> (qt, b, cq); low 4 bits spread (b,cq) across XCDs (id&7 round-robin)
  const int id = blockIdx.x;                     // 0..511
  const int bc = id & 15;
  const int b  = bc >> 2, cq = bc & 3;
  const int qt = id >> 4;                        // 0..31
  const int q0 = qt * 128 + w * 32;              // wave's 32 q-rows

  const u16* Qb = Qg + (size_t)(b * 4096) * 32;
  const u16* Kb = Kg + (size_t)(b * 4096) * 32;
  const u16* Vb = Vfrag + (size_t)b * (64 * 256 * 64);
  const float gm = gamma[0];

  // Q B-frags: b[d = ds*16 + h32*8 + j][q = m32]
  bf16x8 qa0 = *(const bf16x8*)(Qb + (size_t)(q0 + m32) * 32 + h32 * 8);
  bf16x8 qa1 = *(const bf16x8*)(Qb + (size_t)(q0 + m32) * 32 + 16 + h32 * 8);

  // ---- prologue: stage V(0) -> Vl[0] (wave stages chunks p=2w,2w+1); K(0) ----
  {
    const u16* vs = Vb + (size_t)(w * 2) * 2048 + cq * 512 + lane * 8;
    load_lds16(vs,        &Vl[0][(w * 2) * 512]);
    load_lds16(vs + 2048, &Vl[0][(w * 2 + 1) * 512]);
  }
  asm volatile("" ::: "memory");
  // K A-frags: a[k-row = kc*32 + m32][d = ds*16 + h32*8 + j]
  bf16x8 kf0, kf1, kf2, kf3;
  {
    const u16* kp = Kb + (size_t)m32 * 32 + h32 * 8;
    kf0 = *(const bf16x8*)(kp);                 // kc=0, ds=0
    kf1 = *(const bf16x8*)(kp + 16);            // kc=0, ds=1
    kf2 = *(const bf16x8*)(kp + 1024);          // kc=1, ds=0  (+32 rows * 32)
    kf3 = *(const bf16x8*)(kp + 1024 + 16);     // kc=1, ds=1
  }

  f32x16 acc0, acc1;                             // 32q x 64c: cb=0,1
  #pragma unroll
  for (int i = 0; i < 16; ++i){ acc0[i] = 0.f; acc1[i] = 0.f; }
  float ls = 0.f;
  const f32x16 zero16 = (f32x16){0.f,0.f,0.f,0.f,0.f,0.f,0.f,0.f,
                                 0.f,0.f,0.f,0.f,0.f,0.f,0.f,0.f};

  int buf = 0;
  for (int t = 0; t < 64; ++t){
    // drain own stage(t) (the 2 oldest tracked vm ops); newer ops ride
    asm volatile("s_waitcnt vmcnt(4)" ::: "memory");
    BARRIER_LGKM();                              // Vl[buf] staged by all 4 waves

    // stage V(t+1) into Vl[buf^1] (t=63: dummy re-stage of t=63; counts uniform)
    const int tn = (t < 63) ? t + 1 : 63;
    {
      const u16* vs = Vb + (size_t)tn * 16384 + (size_t)(w * 2) * 2048 + cq * 512 + lane * 8;
      load_lds16(vs,        &Vl[buf ^ 1][(w * 2) * 512]);
      load_lds16(vs + 2048, &Vl[buf ^ 1][(w * 2 + 1) * 512]);
    }
    asm volatile("" ::: "memory");

    // K(t+1) prefetch (self-guarded by compiler waits; dummy at t=63)
    bf16x8 nf0, nf1, nf2, nf3;
    {
      const u16* kp = Kb + ((size_t)(tn * 64) + m32) * 32 + h32 * 8;
      nf0 = *(const bf16x8*)(kp);
      nf1 = *(const bf16x8*)(kp + 16);
      nf2 = *(const bf16x8*)(kp + 1024);
      nf3 = *(const bf16x8*)(kp + 1024 + 16);
    }
    asm volatile("s_waitcnt vmcnt(6)" ::: "memory");   // hint: K(t) done

    // ---- swapped QK: s[k][q], chunk0 = k 0..31, chunk1 = k 32..63 ----
    f32x16 s0 = __builtin_amdgcn_mfma_f32_32x32x16_bf16(kf0, qa0, zero16, 0, 0, 0);
    s0        = __builtin_amdgcn_mfma_f32_32x32x16_bf16(kf1, qa1, s0,     0, 0, 0);
    f32x16 s1 = __builtin_amdgcn_mfma_f32_32x32x16_bf16(kf2, qa0, zero16, 0, 0, 0);
    s1        = __builtin_amdgcn_mfma_f32_32x32x16_bf16(kf3, qa1, s1,     0, 0, 0);

    // ---- p = exp2(s+SH); lsum; pack to bf16 pairs ----
    u32 wd0[8], wd1[8];
    #pragma unroll
    for (int i = 0; i < 8; ++i){
      float a0 = __builtin_amdgcn_exp2f(s0[2*i]   + SH);
      float a1 = __builtin_amdgcn_exp2f(s0[2*i+1] + SH);
      float b0 = __builtin_amdgcn_exp2f(s1[2*i]   + SH);
      float b1 = __builtin_amdgcn_exp2f(s1[2*i+1] + SH);
      ls += (a0 + a1) + (b0 + b1);
      asm("v_cvt_pk_bf16_f32 %0, %1, %2" : "=v"(wd0[i]) : "v"(a0), "v"(a1));
      asm("v_cvt_pk_bf16_f32 %0, %1, %2" : "=v"(wd1[i]) : "v"(b0), "v"(b1));
    }
    // ---- redistribute across h32 halves: pairs (0,2),(1,3),(4,6),(5,7) ----
    asm("v_permlane32_swap_b32 %0, %1" : "+v"(wd0[0]), "+v"(wd0[2]));
    asm("v_permlane32_swap_b32 %0, %1" : "+v"(wd0[1]), "+v"(wd0[3]));
    asm("v_permlane32_swap_b32 %0, %1" : "+v"(wd0[4]), "+v"(wd0[6]));
    asm("v_permlane32_swap_b32 %0, %1" : "+v"(wd0[5]), "+v"(wd0[7]));
    asm("v_permlane32_swap_b32 %0, %1" : "+v"(wd1[0]), "+v"(wd1[2]));
    asm("v_permlane32_swap_b32 %0, %1" : "+v"(wd1[1]), "+v"(wd1[3]));
    asm("v_permlane32_swap_b32 %0, %1" : "+v"(wd1[4]), "+v"(wd1[6]));
    asm("v_permlane32_swap_b32 %0, %1" : "+v"(wd1[5]), "+v"(wd1[7]));
    bf16x8 pa0 = __builtin_bit_cast(bf16x8, make_uint4(wd0[0], wd0[1], wd0[2], wd0[3]));
    bf16x8 pa1 = __builtin_bit_cast(bf16x8, make_uint4(wd0[4], wd0[5], wd0[6], wd0[7]));
    bf16x8 pa2 = __builtin_bit_cast(bf16x8, make_uint4(wd1[0], wd1[1], wd1[2], wd1[3]));
    bf16x8 pa3 = __builtin_bit_cast(bf16x8, make_uint4(wd1[4], wd1[5], wd1[6], wd1[7]));

    // ---- PV: acc[cb] += pa[ks] x V(ks,cb) from Vl[buf] ----
    #pragma unroll
    for (int cb = 0; cb < 2; ++cb){
      bf16x8 vf0 = *(const bf16x8*)&Vl[buf][((0*2 + h32) * 64 + cb * 32 + m32) * 8];
      bf16x8 vf1 = *(const bf16x8*)&Vl[buf][((1*2 + h32) * 64 + cb * 32 + m32) * 8];
      bf16x8 vf2 = *(const bf16x8*)&Vl[buf][((2*2 + h32) * 64 + cb * 32 + m32) * 8];
      bf16x8 vf3 = *(const bf16x8*)&Vl[buf][((3*2 + h32) * 64 + cb * 32 + m32) * 8];
      f32x16& ac = cb ? acc1 : acc0;
      ac = __builtin_amdgcn_mfma_f32_32x32x16_bf16(pa0, vf0, ac, 0, 0, 0);
      ac = __builtin_amdgcn_mfma_f32_32x32x16_bf16(pa1, vf1, ac, 0, 0, 0);
      ac = __builtin_amdgcn_mfma_f32_32x32x16_bf16(pa2, vf2, ac, 0, 0, 0);
      ac = __builtin_amdgcn_mfma_f32_32x32x16_bf16(pa3, vf3, ac, 0, 0, 0);
    }

    kf0 = nf0; kf1 = nf1; kf2 = nf2; kf3 = nf3;
    buf ^= 1;
  }

  // ================= epilogue: l complete locally, direct write =================
  float ltot = ls + __shfl_xor(ls, 32);          // lanes m32 & m32+32 -> l[q=m32]

  const size_t rbase = (size_t)(b * 4096 + qt * 128 + w * 32);
  const int col = cq * 64 + m32;                 // + cb*32
  #pragma unroll
  for (int cb = 0; cb < 2; ++cb){
    const f32x16& ac = cb ? acc1 : acc0;
    #pragma unroll
    for (int rg = 0; rg < 16; ++rg){
      int rowq = (rg & 3) + 8 * (rg >> 2) + 4 * h32;     // 32x32 C-layout row
      float lr = __shfl(ltot, rowq);                     // l for this acc row
      size_t off = (rbase + rowq) * 256 + col + cb * 32;
      out[off] = ac[rg] * (gm / lr) + x[off];
    }
  }
}

extern "C" void kernel_launch(void* const* d_in, const int* in_sizes, int n_in,
                              void* d_out, int out_size, void* d_ws, size_t ws_size,
                              hipStream_t stream) {
  const float* x     = (const float*)d_in[0];
  const float* Wf    = (const float*)d_in[1];
  const float* Wg    = (const float*)d_in[2];
  const float* Wh    = (const float*)d_in[3];
  const float* gamma = (const float*)d_in[4];
  float* out = (float*)d_out;

  u16* p = (u16*)d_ws;
  u16* Qg    = p;  p += 16384 * 32;               // 1 MB
  u16* Kg    = p;  p += 16384 * 32;               // 1 MB
  u16* Vfrag = p;  p += 4 * 64 * 256 * 64;        // 8 MB, fragment-major
  u16* Wfrag = p;  p += 20 * 8 * 64 * 8;          // 160 KB, fragment-major

  prep_kernel<<<20, 512, 0, stream>>>(Wf, Wg, Wh, Wfrag);
  proj_kernel<<<256, 512, 0, stream>>>(x, Wfrag, Qg, Kg, Vfrag);
  flash_kernel<<<512, 256, 0, stream>>>(Qg, Kg, Vfrag, x, gamma, out);
}

// Round 10
// 148.712 us; speedup vs baseline: 1.2187x; 1.2187x over previous
//
#include <hip/hip_runtime.h>
#include <hip/hip_bf16.h>

typedef __bf16 bf16x8 __attribute__((ext_vector_type(8)));
typedef float f32x4 __attribute__((ext_vector_type(4)));
typedef float f32x16 __attribute__((ext_vector_type(16)));
typedef unsigned short u16;
typedef unsigned int u32;

__device__ __forceinline__ u16 f2bf_rne(float f){
  union { float f; u32 u; } v; v.f = f;
  u32 r = v.u + 0x7fffu + ((v.u >> 16) & 1u);
  return (u16)(r >> 16);
}
// pack hi16(a)|hi16(b)<<16 in ONE v_perm_b32 (truncation; P feeds attention weights)
__device__ __forceinline__ u32 pack2(float a, float b){
  return __builtin_amdgcn_perm(__float_as_uint(a), __float_as_uint(b), 0x03020706u);
}
// workgroup barrier WITHOUT vmcnt drain (LDS visibility only): in-flight global
// loads (K/V register prefetches) ride through; compiler vmcnt-waits at use.
#define BARRIER_LGKM() asm volatile("s_waitcnt lgkmcnt(0)\n\ts_barrier" ::: "memory")

// ------------- prep: Wfrag = [Wh|Wf|Wg]^T in MFMA B-fragment order -------------
// Wfrag[cc(20)][kk(8)][lane(64)][j(8)] bf16; lane=(quad,L):
//   element = Wcat[k = kk*32 + quad*8 + j][n = cc*16 + L]
__global__ __launch_bounds__(512) void prep_kernel(
    const float* __restrict__ Wf, const float* __restrict__ Wg,
    const float* __restrict__ Wh, u16* __restrict__ Wfrag){
  const int cc = blockIdx.x;             // 20
  const int t = threadIdx.x;             // 512 = kk(8) x lane(64)
  const int kk = t >> 6, lane = t & 63;
  const int L = lane & 15, quad = lane >> 4;
  const int n = cc * 16 + L;
  u32 pk[4];
  #pragma unroll
  for (int j2 = 0; j2 < 4; ++j2){
    float v[2];
    #pragma unroll
    for (int h = 0; h < 2; ++h){
      int k = kk * 32 + quad * 8 + j2 * 2 + h;
      if (n < 256)      v[h] = Wh[k * 256 + n];
      else if (n < 288) v[h] = Wf[k * 32 + (n - 256)];
      else              v[h] = Wg[k * 32 + (n - 288)];
    }
    pk[j2] = (u32)f2bf_rne(v[0]) | ((u32)f2bf_rne(v[1]) << 16);
  }
  uint4* dst = (uint4*)(Wfrag + ((size_t)(cc * 8 + kk) * 64 + lane) * 8);
  *dst = make_uint4(pk[0], pk[1], pk[2], pk[3]);
}

// ---------------- projection: h/f/g via MFMA, 512 thr / 8 waves ----------------
// Qg pre-scaled by log2(e). V emitted fragment-major per 64-row group:
// Vfrag[g64][p_hi(8)][c(256)][j(8)], p = ((tn&15)<<2)|(tn>>4).
__global__ __launch_bounds__(512) void proj_kernel(
    const float* __restrict__ x, const u16* __restrict__ Wfrag,
    u16* __restrict__ Qg, u16* __restrict__ Kg, u16* __restrict__ Vfrag)
{
  __shared__ __align__(16) u16 smem[256 * 72];   // 36 KB, two phases
  u16 (*xb)[264] = (u16(*)[264])smem;
  u16 (*Vr)[72]  = (u16(*)[72])smem;

  const int tid = threadIdx.x;
  const int lane = tid & 63, wave = tid >> 6;
  const int L = lane & 15, quad = lane >> 4;
  const int rowgrp = wave >> 1, colhalf = wave & 1;
  const int n0 = blockIdx.x * 64;

  const float4* xsrc = (const float4*)(x + (size_t)n0 * 256);
  #pragma unroll
  for (int j = 0; j < 8; ++j){
    int idx = j * 512 + tid;
    int row = idx >> 6, col4 = idx & 63;
    float4 v = xsrc[idx];
    u32 p0 = (u32)f2bf_rne(v.x) | ((u32)f2bf_rne(v.y) << 16);
    u32 p1 = (u32)f2bf_rne(v.z) | ((u32)f2bf_rne(v.w) << 16);
    *(uint2*)&xb[row][col4 * 4] = make_uint2(p0, p1);
  }
  __syncthreads();

  f32x4 acc[10];
  #pragma unroll
  for (int cc = 0; cc < 10; ++cc) acc[cc] = (f32x4){0.f, 0.f, 0.f, 0.f};

  #pragma unroll
  for (int kk = 0; kk < 8; ++kk){
    bf16x8 a = *(const bf16x8*)&xb[rowgrp * 16 + L][kk * 32 + quad * 8];
    #pragma unroll
    for (int cc = 0; cc < 10; ++cc){
      int ccg = colhalf * 10 + cc;
      bf16x8 bfr = *(const bf16x8*)(Wfrag + ((size_t)(ccg * 8 + kk) * 64 + lane) * 8);
      acc[cc] = __builtin_amdgcn_mfma_f32_16x16x32_bf16(a, bfr, acc[cc], 0, 0, 0);
    }
  }

  if (colhalf){
    #pragma unroll
    for (int cc = 6; cc < 10; ++cc){
      int ccg = 10 + cc;                                  // 16..19
      u16* dst = (ccg < 18) ? Kg : Qg;                    // K = f, Q = g
      float sc = (ccg < 18) ? 1.0f : 1.44269504088896f;
      int c = (ccg & 1) * 16 + L;
      #pragma unroll
      for (int r = 0; r < 4; ++r){
        int row = n0 + rowgrp * 16 + quad * 4 + r;
        dst[(size_t)row * 32 + c] = f2bf_rne(acc[cc][r] * sc);
      }
    }
  }

  __syncthreads();   // xb consumed; reuse smem as Vr

  {
    const int cmax = colhalf ? 6 : 10;
    for (int cc = 0; cc < cmax; ++cc){
      int ccg = colhalf * 10 + cc;
      int c = ccg * 16 + L;
      #pragma unroll
      for (int r = 0; r < 4; ++r){
        int tn = rowgrp * 16 + quad * 4 + r;
        int p  = ((tn & 15) << 2) | (tn >> 4);
        Vr[c][p] = f2bf_rne(acc[cc][r]);
      }
    }
  }
  __syncthreads();

  u16* Vblk = Vfrag + (size_t)blockIdx.x * (256 * 64);
  #pragma unroll
  for (int i = 0; i < 4; ++i){
    int idx = i * 512 + tid;
    *(uint4*)(Vblk + (size_t)idx * 8) = *(const uint4*)&Vr[idx & 255][(idx >> 8) * 8];
  }
}

// ---- flash v10: PRODUCER-CONSUMER wave specialization, q-tile 64, 2 tiles/iter -
// WHY (R0-R9): R9 (no P round-trip) proved the barrier structure wasn't the only
// cost (4x softmax dup made it VALU-bound, 96us). R0's 4000 cyc/iter fits two
// models: L2 delivery (~24.6 B/cyc/CU) or per-wave serial chain x waves/SIMD
// (every wave runs QK->exp->Pstore->barrier->Pload->PV serially). This kernel
// DISCRIMINATES: same bytes/iter as R0 (V 64KB + K 16KB per 2-tile iter), same
// barrier count (1/iter, 32 iters), but the chain is SPLIT across wave roles:
//   waves 0-3 (producers): QK (8 mfma 16x16x32 for 64q x 2 tiles), exp2/pack,
//     P store to Plds, lsum. Own k/Q registers; prefetch K(it+1).
//   waves 4-7 (consumers): PV (32 mfma 32x32x16: 64q x 64c each, cols cw*64),
//     P from Plds, V fragments in registers; prefetch V(it+1).
// Each SIMD hosts 1 producer + 1 consumer (waves i, i+4) -> exp/trans work and
// PV MFMA issue CONCURRENTLY instead of serially within each wave.
// Slab safety (2 bufs x 2 tiles): producer writes slab it&1 pre-barrier(it);
// consumer reads it post-barrier(it), drains own reads (lgkm) by barrier(it+1);
// producer rewrites that slab at it+2 -> one full barrier after last reads.
// Softmax computed ONCE (no duplication). Epilogue: consumers deposit O into
// Osh (overlays Plds post-drain), producers provide l via Lsh; single scale at
// the coalesced out-write (no half-merge needed; consumers cover all 64 rows).
__global__ __launch_bounds__(512) void flash_kernel(
    const u16* __restrict__ Qg, const u16* __restrict__ Kg, const u16* __restrict__ Vfrag,
    const float* __restrict__ x, const float* __restrict__ gamma, float* __restrict__ out)
{
  constexpr float SH = -92.33248261689366f;      // -64*log2(e); s already log2-scaled
  __shared__ __align__(16) char smem[65536];     // Plds 36864 B overlaid by Osh 64 KB
  u16 (*Plds)[2][64][72] = (u16 (*)[2][64][72])smem;   // [buf][tile][row][72]
  float (*Osh)[256] = (float (*)[256])smem;
  __shared__ float Lsh[64];

  const int tid = threadIdx.x, lane = tid & 63, wave = tid >> 6;
  const int L = lane & 15, quad = lane >> 4;
  const int m32 = lane & 31, h32 = lane >> 5;
  const bool producer = wave < 4;
  const int pw = wave & 3;                       // producer q-group / consumer c-group

  // XCD swizzle: id&7 -> XCD; 2 XCDs per batch (V+K+Q working set ~2.5MB < 4MB L2)
  const int id = blockIdx.x;                     // 0..255
  const int xcd = id & 7;
  const int b = xcd >> 1;
  const int qt = (xcd & 1) * 32 + (id >> 3);     // 0..63
  const int q0 = qt * 64;

  const u16* Qb = Qg + (size_t)(b * 4096) * 32;
  const u16* Kb = Kg + (size_t)(b * 4096) * 32;
  const u16* Vb = Vfrag + (size_t)b * (64 * 256 * 64);
  const float gm = gamma[0];

  // ---- prologue ----
  bf16x8 qa;
  bf16x8 kcA0, kcA1, kcA2, kcA3, kcB0, kcB1, kcB2, kcB3;
  bf16x8 vfA[8], vfB[8];
  if (producer){
    qa = *(const bf16x8*)(Qb + (size_t)(q0 + pw * 16 + L) * 32 + quad * 8);
    const u16* kpA = Kb + (size_t)(0 * 64 + L) * 32 + quad * 8;
    kcA0 = *(const bf16x8*)(kpA);
    kcA1 = *(const bf16x8*)(kpA + 512);
    kcA2 = *(const bf16x8*)(kpA + 1024);
    kcA3 = *(const bf16x8*)(kpA + 1536);
    const u16* kpB = kpA + 2048;
    kcB0 = *(const bf16x8*)(kpB);
    kcB1 = *(const bf16x8*)(kpB + 512);
    kcB2 = *(const bf16x8*)(kpB + 1024);
    kcB3 = *(const bf16x8*)(kpB + 1536);
  } else {
    #pragma unroll
    for (int ks = 0; ks < 4; ++ks){
      const u16* vrow = Vb + (size_t)((ks * 2 + h32) * 256 + pw * 64 + m32) * 8;
      vfA[ks * 2]     = *(const bf16x8*)(vrow);
      vfA[ks * 2 + 1] = *(const bf16x8*)(vrow + 32 * 8);
      vfB[ks * 2]     = *(const bf16x8*)(vrow + 16384);
      vfB[ks * 2 + 1] = *(const bf16x8*)(vrow + 16384 + 32 * 8);
    }
  }

  f32x16 acc[4];                                  // consumers: [qi*2+ci] 64q x 64c
  #pragma unroll
  for (int t = 0; t < 4; ++t)
    #pragma unroll
    for (int i = 0; i < 16; ++i) acc[t][i] = 0.f;
  float lsum[4] = {0.f, 0.f, 0.f, 0.f};           // producers
  const f32x4 zero = (f32x4){0.f, 0.f, 0.f, 0.f};

  for (int it = 0; it < 32; ++it){
    u16 (*PwA)[72] = Plds[it & 1][0];
    u16 (*PwB)[72] = Plds[it & 1][1];

    if (producer){
      // ---- QK^T for tiles 2it (A), 2it+1 (B); s log2-scaled via Qg ----
      f32x4 sA0 = __builtin_amdgcn_mfma_f32_16x16x32_bf16(qa, kcA0, zero, 0, 0, 0);
      f32x4 sA1 = __builtin_amdgcn_mfma_f32_16x16x32_bf16(qa, kcA1, zero, 0, 0, 0);
      f32x4 sA2 = __builtin_amdgcn_mfma_f32_16x16x32_bf16(qa, kcA2, zero, 0, 0, 0);
      f32x4 sA3 = __builtin_amdgcn_mfma_f32_16x16x32_bf16(qa, kcA3, zero, 0, 0, 0);
      f32x4 sB0 = __builtin_amdgcn_mfma_f32_16x16x32_bf16(qa, kcB0, zero, 0, 0, 0);
      f32x4 sB1 = __builtin_amdgcn_mfma_f32_16x16x32_bf16(qa, kcB1, zero, 0, 0, 0);
      f32x4 sB2 = __builtin_amdgcn_mfma_f32_16x16x32_bf16(qa, kcB2, zero, 0, 0, 0);
      f32x4 sB3 = __builtin_amdgcn_mfma_f32_16x16x32_bf16(qa, kcB3, zero, 0, 0, 0);

      // ---- K prefetch for it+1 (tiles 2it+2, 2it+3) ----
      if (it < 31){
        const u16* kpa = Kb + (size_t)((2 * it + 2) * 64 + L) * 32 + quad * 8;
        kcA0 = *(const bf16x8*)(kpa);
        kcA1 = *(const bf16x8*)(kpa + 512);
        kcA2 = *(const bf16x8*)(kpa + 1024);
        kcA3 = *(const bf16x8*)(kpa + 1536);
        const u16* kpb = kpa + 2048;
        kcB0 = *(const bf16x8*)(kpb);
        kcB1 = *(const bf16x8*)(kpb + 512);
        kcB2 = *(const bf16x8*)(kpb + 1024);
        kcB3 = *(const bf16x8*)(kpb + 1536);
      }

      // ---- p = exp2(s+SH); lsum; packed P stores (rows pw*16+quad*4+r) ----
      #pragma unroll
      for (int r = 0; r < 4; ++r){
        float a0 = __builtin_amdgcn_exp2f(sA0[r] + SH);
        float a1 = __builtin_amdgcn_exp2f(sA1[r] + SH);
        float a2 = __builtin_amdgcn_exp2f(sA2[r] + SH);
        float a3 = __builtin_amdgcn_exp2f(sA3[r] + SH);
        float b0 = __builtin_amdgcn_exp2f(sB0[r] + SH);
        float b1 = __builtin_amdgcn_exp2f(sB1[r] + SH);
        float b2 = __builtin_amdgcn_exp2f(sB2[r] + SH);
        float b3 = __builtin_amdgcn_exp2f(sB3[r] + SH);
        lsum[r] += ((a0 + a1) + (a2 + a3)) + ((b0 + b1) + (b2 + b3));
        *(uint2*)&PwA[pw * 16 + quad * 4 + r][L * 4] =
            make_uint2(pack2(a0, a1), pack2(a2, a3));
        *(uint2*)&PwB[pw * 16 + quad * 4 + r][L * 4] =
            make_uint2(pack2(b0, b1), pack2(b2, b3));
      }
    }

    BARRIER_LGKM();   // P(it) visible; K/V register prefetches ride through

    if (!producer){
      // ---- O += P(A) V(A) + P(B) V(B): af from Plds, vf in registers ----
      #pragma unroll
      for (int ks = 0; ks < 4; ++ks){
        bf16x8 af0 = *(const bf16x8*)&PwA[m32][ks * 16 + h32 * 8];
        bf16x8 af1 = *(const bf16x8*)&PwA[32 + m32][ks * 16 + h32 * 8];
        acc[0] = __builtin_amdgcn_mfma_f32_32x32x16_bf16(af0, vfA[ks*2],   acc[0], 0, 0, 0);
        acc[1] = __builtin_amdgcn_mfma_f32_32x32x16_bf16(af0, vfA[ks*2+1], acc[1], 0, 0, 0);
        acc[2] = __builtin_amdgcn_mfma_f32_32x32x16_bf16(af1, vfA[ks*2],   acc[2], 0, 0, 0);
        acc[3] = __builtin_amdgcn_mfma_f32_32x32x16_bf16(af1, vfA[ks*2+1], acc[3], 0, 0, 0);
      }
      #pragma unroll
      for (int ks = 0; ks < 4; ++ks){
        bf16x8 af0 = *(const bf16x8*)&PwB[m32][ks * 16 + h32 * 8];
        bf16x8 af1 = *(const bf16x8*)&PwB[32 + m32][ks * 16 + h32 * 8];
        acc[0] = __builtin_amdgcn_mfma_f32_32x32x16_bf16(af0, vfB[ks*2],   acc[0], 0, 0, 0);
        acc[1] = __builtin_amdgcn_mfma_f32_32x32x16_bf16(af0, vfB[ks*2+1], acc[1], 0, 0, 0);
        acc[2] = __builtin_amdgcn_mfma_f32_32x32x16_bf16(af1, vfB[ks*2],   acc[2], 0, 0, 0);
        acc[3] = __builtin_amdgcn_mfma_f32_32x32x16_bf16(af1, vfB[ks*2+1], acc[3], 0, 0, 0);
      }
      // ---- V prefetch for it+1 (tiles 2it+2, 2it+3) ----
      if (it < 31){
        const u16* Vn = Vb + (size_t)(2 * it + 2) * (256 * 64);
        #pragma unroll
        for (int ks = 0; ks < 4; ++ks){
          const u16* vrow = Vn + (size_t)((ks * 2 + h32) * 256 + pw * 64 + m32) * 8;
          vfA[ks * 2]     = *(const bf16x8*)(vrow);
          vfA[ks * 2 + 1] = *(const bf16x8*)(vrow + 32 * 8);
          vfB[ks * 2]     = *(const bf16x8*)(vrow + 16384);
          vfB[ks * 2 + 1] = *(const bf16x8*)(vrow + 16384 + 32 * 8);
        }
      }
    }
    // no end barrier: 2-deep P slabs; rewrite gated by next barrier (see header)
  }

  // ================= epilogue =================
  BARRIER_LGKM();   // all PV ds-reads retired; Plds region reusable as Osh

  if (producer){
    // l over full k: reduce the 16 L-partials per (quad,r); rows pw*16+quad*4+r
    #pragma unroll
    for (int r = 0; r < 4; ++r){
      lsum[r] += __shfl_xor(lsum[r], 1);
      lsum[r] += __shfl_xor(lsum[r], 2);
      lsum[r] += __shfl_xor(lsum[r], 4);
      lsum[r] += __shfl_xor(lsum[r], 8);
    }
    if (L == 0){
      #pragma unroll
      for (int r = 0; r < 4; ++r) Lsh[pw * 16 + quad * 4 + r] = lsum[r];
    }
  } else {
    // consumers deposit O (64 rows x own 64 cols) into Osh
    #pragma unroll
    for (int t = 0; t < 4; ++t){
      const int qi = t >> 1, ci = t & 1;
      #pragma unroll
      for (int rg = 0; rg < 16; ++rg){
        int row = qi * 32 + (rg & 3) + 8 * (rg >> 2) + 4 * h32;   // 32x32 C-layout
        Osh[row][pw * 64 + ci * 32 + m32] = acc[t][rg];
      }
    }
  }
  __syncthreads();
  if (wave == 0) Lsh[lane] = gm / Lsh[lane];     // per-row scale factor
  __syncthreads();
  // coalesced: out = Osh * (gamma/l) + x
  const size_t base = ((size_t)(b * 4096) + q0) * 256;
  const float4* xs = (const float4*)(x + base);
  float4* od = (float4*)(out + base);
  const float4* Of = (const float4*)&Osh[0][0];
  #pragma unroll
  for (int i = 0; i < 8; ++i){
    int idx = i * 512 + tid;
    float li = Lsh[idx >> 6];
    float4 o = Of[idx], xv = xs[idx];
    o.x = o.x * li + xv.x; o.y = o.y * li + xv.y;
    o.z = o.z * li + xv.z; o.w = o.w * li + xv.w;
    od[idx] = o;
  }
}

extern "C" void kernel_launch(void* const* d_in, const int* in_sizes, int n_in,
                              void* d_out, int out_size, void* d_ws, size_t ws_size,
                              hipStream_t stream) {
  const float* x     = (const float*)d_in[0];
  const float* Wf    = (const float*)d_in[1];
  const float* Wg    = (const float*)d_in[2];
  const float* Wh    = (const float*)d_in[3];
  const float* gamma = (const float*)d_in[4];
  float* out = (float*)d_out;

  u16* p = (u16*)d_ws;
  u16* Qg    = p;  p += 16384 * 32;               // 1 MB
  u16* Kg    = p;  p += 16384 * 32;               // 1 MB
  u16* Vfrag = p;  p += 4 * 64 * 256 * 64;        // 8 MB, fragment-major
  u16* Wfrag = p;  p += 20 * 8 * 64 * 8;          // 160 KB, fragment-major

  prep_kernel<<<20, 512, 0, stream>>>(Wf, Wg, Wh, Wfrag);
  proj_kernel<<<256, 512, 0, stream>>>(x, Wfrag, Qg, Kg, Vfrag);
  flash_kernel<<<256, 512, 0, stream>>>(Qg, Kg, Vfrag, x, gamma, out);
}